// Round 4
// baseline (473.327 us; speedup 1.0000x reference)
//
#include <hip/hip_runtime.h>
#include <stdint.h>

#define BB 2
#define LL 2048
#define DD 1024
#define NHH 16
#define HSS 64

typedef __bf16 bf16x8 __attribute__((ext_vector_type(8)));
typedef float f32x4 __attribute__((ext_vector_type(4)));

#define NEG_SENTINEL (-1e30f)

// Load 8 consecutive elements as bf16x8, converting from fp32 if needed.
__device__ __forceinline__ bf16x8 load8(const float* p) {
  float4 f0 = *(const float4*)p;
  float4 f1 = *(const float4*)(p + 4);
  bf16x8 v;
  v[0] = (__bf16)f0.x; v[1] = (__bf16)f0.y; v[2] = (__bf16)f0.z; v[3] = (__bf16)f0.w;
  v[4] = (__bf16)f1.x; v[5] = (__bf16)f1.y; v[6] = (__bf16)f1.z; v[7] = (__bf16)f1.w;
  return v;
}
__device__ __forceinline__ bf16x8 load8(const __bf16* p) {
  return *(const bf16x8*)p;
}

// ---------------------------------------------------------------- GEMM
// C[M,N] = A[M,K] @ B[K,N] + bias. A is fp32 or bf16 (template); B/bias fp32.
// B transposed into LDS at staging (converted to bf16). 64x64 tile, BK=32,
// 4 waves (each 32x32).
// mode 0: scatter qkv -> Q[b,h,l,d](bf16), K[b,h,l,d](bf16), Vt[b,h,d,l](bf16)
// mode 1: out[M,N] row-major fp32
template <typename AT>
__global__ __launch_bounds__(256) void gemm_k(
    const AT* __restrict__ A, const float* __restrict__ Bg,
    const float* __restrict__ bias, int M, int N, int K, int mode,
    float* __restrict__ out, __bf16* __restrict__ Qo,
    __bf16* __restrict__ Ko, __bf16* __restrict__ Vto) {
  // pitch 40 bf16 = 80B: multiple of 16B (aligned b128 frag reads)
  __shared__ __align__(16) __bf16 As[64 * 40];  // As[m][k]
  __shared__ __align__(16) __bf16 Bs[64 * 40];  // Bs[n][k]  (transposed at stage)
  int t = threadIdx.x;
  int wave = t >> 6, lane = t & 63, qd = lane >> 4, lr = lane & 15;
  int m0 = blockIdx.y * 64, n0 = blockIdx.x * 64;
  int wm = (wave >> 1) * 32, wn = (wave & 1) * 32;
  f32x4 acc[2][2] = {};
  int sr = t >> 2, sc = (t & 3) * 8;   // A stage: 64 rows x 32 cols, 8 elem/thread
  int kk = t >> 3, nn = (t & 7) * 8;   // B stage: 32 rows x 64 cols, 8 elem/thread
  const AT* Ap = A + (size_t)(m0 + sr) * K + sc;
  const float* Bp = Bg + (size_t)kk * N + n0 + nn;

  for (int k0 = 0; k0 < K; k0 += 32) {
    __syncthreads();
    *(bf16x8*)&As[sr * 40 + sc] = load8(Ap + k0);
    bf16x8 bv = load8(Bp + (size_t)k0 * N);
#pragma unroll
    for (int j = 0; j < 8; j++) Bs[(nn + j) * 40 + kk] = bv[j];  // transpose scatter
    __syncthreads();
    // A-frag: m = lane&15, k = quad*8+j ; B-frag: n = lane&15, k = quad*8+j
    bf16x8 a0 = *(const bf16x8*)&As[(wm + lr) * 40 + qd * 8];
    bf16x8 a1 = *(const bf16x8*)&As[(wm + 16 + lr) * 40 + qd * 8];
    bf16x8 b0 = *(const bf16x8*)&Bs[(wn + lr) * 40 + qd * 8];
    bf16x8 b1 = *(const bf16x8*)&Bs[(wn + 16 + lr) * 40 + qd * 8];
    acc[0][0] = __builtin_amdgcn_mfma_f32_16x16x32_bf16(a0, b0, acc[0][0], 0, 0, 0);
    acc[0][1] = __builtin_amdgcn_mfma_f32_16x16x32_bf16(a0, b1, acc[0][1], 0, 0, 0);
    acc[1][0] = __builtin_amdgcn_mfma_f32_16x16x32_bf16(a1, b0, acc[1][0], 0, 0, 0);
    acc[1][1] = __builtin_amdgcn_mfma_f32_16x16x32_bf16(a1, b1, acc[1][1], 0, 0, 0);
  }
  // C/D layout: col = lane&15, row = quad*4 + reg   (m89/m91-verified)
#pragma unroll
  for (int mt = 0; mt < 2; mt++) {
#pragma unroll
    for (int nt = 0; nt < 2; nt++) {
#pragma unroll
      for (int r = 0; r < 4; r++) {
        int row = m0 + wm + mt * 16 + qd * 4 + r;
        int col = n0 + wn + nt * 16 + lr;
        float v = acc[mt][nt][r] + bias[col];
        if (mode == 1) {
          out[(size_t)row * N + col] = v;
        } else {
          __bf16 bvv = (__bf16)v;
          int b = row >> 11, l = row & 2047;  // M = B*L, L = 2048
          if (col < DD) {
            int h = col >> 6, d = col & 63;
            Qo[(((size_t)(b * NHH + h)) * LL + l) * HSS + d] = bvv;
          } else if (col < 2 * DD) {
            int c2 = col - DD;
            int h = c2 >> 6, d = c2 & 63;
            Ko[(((size_t)(b * NHH + h)) * LL + l) * HSS + d] = bvv;
          } else {
            int c3 = col - 2 * DD;
            int h = c3 >> 6, d = c3 & 63;
            Vto[(((size_t)(b * NHH + h)) * HSS + d) * LL + l] = bvv;  // V transposed
          }
        }
      }
    }
  }
}

// ---------------------------------------------------------------- flash attn
// Srel[i,j] = q_i . Er[L-1-i+j]  (skew identity, j<=i). Block = (i-tile 64, b*h).
// Wave w owns rows [i0+16w, i0+16w+16). Per 64-col j-tile:
//   S = Q Kt (8 mfma); QEwin = Q ErWin^T (10 mfma, 80-col window, cbase=48-16w);
//   rel diagonal gathered via register shuffles; online softmax (quad shuffles);
//   P -> per-wave bf16 LDS -> A-frag; O += P V (8 mfma).
// Q/K/Vt are bf16 (workspace); Er is fp32 (input, converted at staging).
__global__ __launch_bounds__(256) void flash_k(
    const __bf16* __restrict__ Qg, const __bf16* __restrict__ Kg,
    const __bf16* __restrict__ Vtg, const float* __restrict__ Erg,
    __bf16* __restrict__ Yg) {
  __shared__ __align__(16) __bf16 Kld[64 * 72];    // [j][d], pitch 144B
  __shared__ __align__(16) __bf16 Vld[64 * 72];    // [d][j]
  __shared__ __align__(16) __bf16 Erld[128 * 72];  // [e][d]
  __shared__ __align__(16) __bf16 Pball[4][16 * 72];  // per-wave P

  int i0 = (gridDim.x - 1 - blockIdx.x) * 64;  // heavy tiles dispatch first
  int bh = blockIdx.y;
  const __bf16* Qh = Qg + (size_t)bh * LL * HSS;
  const __bf16* Kh = Kg + (size_t)bh * LL * HSS;
  const __bf16* Vth = Vtg + (size_t)bh * HSS * LL;
  int b = bh >> 4, h = bh & 15;
  int t = threadIdx.x, wave = t >> 6, lane = t & 63, qd = lane >> 4, lr = lane & 15;
  __bf16* Pb = &Pball[wave][0];

  // Q fragments for this wave's 16 rows (regs for whole kernel)
  bf16x8 aq[2];
  {
    const __bf16* qrow = Qh + (size_t)(i0 + wave * 16 + lr) * HSS + qd * 8;
    aq[0] = *(const bf16x8*)qrow;
    aq[1] = *(const bf16x8*)(qrow + 32);
  }
  f32x4 oacc[4] = {};
  float m_run[4], l_run[4];
#pragma unroll
  for (int r = 0; r < 4; r++) { m_run[r] = NEG_SENTINEL; l_run[r] = 0.f; }
  int cbase = 48 - wave * 16;

  for (int j0 = 0; j0 <= i0; j0 += 64) {
    __syncthreads();  // prev iter's Kld/Vld/Erld reads done before restage
    {  // stage K rows, Vt rows, Er window (ebase = L-64-i0+j0 >= 0 always)
      int jj = t >> 2, hf = t & 3;
      *(bf16x8*)&Kld[jj * 72 + hf * 16] = *(const bf16x8*)&Kh[(size_t)(j0 + jj) * HSS + hf * 16];
      *(bf16x8*)&Kld[jj * 72 + hf * 16 + 8] = *(const bf16x8*)&Kh[(size_t)(j0 + jj) * HSS + hf * 16 + 8];
      *(bf16x8*)&Vld[jj * 72 + hf * 16] = *(const bf16x8*)&Vth[(size_t)jj * LL + j0 + hf * 16];
      *(bf16x8*)&Vld[jj * 72 + hf * 16 + 8] = *(const bf16x8*)&Vth[(size_t)jj * LL + j0 + hf * 16 + 8];
      int er = t >> 1, ec = (t & 1) * 32;
      int e = LL - 64 - i0 + j0 + er;
      if (e < LL) {
#pragma unroll
        for (int kx = 0; kx < 4; kx++)
          *(bf16x8*)&Erld[er * 72 + ec + kx * 8] = load8(&Erg[(size_t)e * HSS + ec + kx * 8]);
      } else {  // e>=L rows correspond only to causally-masked entries
        bf16x8 z;
#pragma unroll
        for (int q = 0; q < 8; q++) z[q] = (__bf16)0.f;
#pragma unroll
        for (int kx = 0; kx < 4; kx++) *(bf16x8*)&Erld[er * 72 + ec + kx * 8] = z;
      }
    }
    __syncthreads();

    // QK^T: 4 col-tiles x 2 k-chunks
    f32x4 sacc[4] = {};
#pragma unroll
    for (int ct = 0; ct < 4; ct++)
#pragma unroll
      for (int kc = 0; kc < 2; kc++) {
        bf16x8 bk = *(const bf16x8*)&Kld[(ct * 16 + lr) * 72 + kc * 32 + qd * 8];
        sacc[ct] = __builtin_amdgcn_mfma_f32_16x16x32_bf16(aq[kc], bk, sacc[ct], 0, 0, 0);
      }
    // rel: 5 col-tiles over the 80-col Er window starting at cbase
    f32x4 racc[5] = {};
#pragma unroll
    for (int ct = 0; ct < 5; ct++)
#pragma unroll
      for (int kc = 0; kc < 2; kc++) {
        bf16x8 be = *(const bf16x8*)&Erld[(cbase + ct * 16 + lr) * 72 + kc * 32 + qd * 8];
        racc[ct] = __builtin_amdgcn_mfma_f32_16x16x32_bf16(aq[kc], be, racc[ct], 0, 0, 0);
      }

    // Rel diagonal gather via shuffles.
    // Reader (qd,lr), row tr=qd*4+r, col tj=ct2*16+lr needs QE[tr][lc=15-tr+tj],
    // held in racc[ct2 + (base>>4)][r] of lane qd*16 + (base&15), base=15-tr+lr.
    float sv[4][4];
#pragma unroll
    for (int r = 0; r < 4; r++) {
      int tr = qd * 4 + r;
      int base = 15 - tr + lr;            // in [0,30]
      int src = qd * 16 + (base & 15);
      int hi = base >> 4;                  // 0 or 1
      float sh[5];
#pragma unroll
      for (int ct = 0; ct < 5; ct++) sh[ct] = __shfl(racc[ct][r], src, 64);
#pragma unroll
      for (int ct2 = 0; ct2 < 4; ct2++) {
        float rel = hi ? sh[ct2 + 1] : sh[ct2];
        float v = (sacc[ct2][r] + rel) * 0.125f;
        int gi = i0 + wave * 16 + tr, gj = j0 + ct2 * 16 + lr;
        sv[ct2][r] = (gj <= gi) ? v : NEG_SENTINEL;
      }
    }

    // online softmax; each row lives in one 16-lane quad at one reg
    float mnew[4], alpha[4], psum[4];
#pragma unroll
    for (int r = 0; r < 4; r++) {
      float mx = fmaxf(fmaxf(sv[0][r], sv[1][r]), fmaxf(sv[2][r], sv[3][r]));
#pragma unroll
      for (int off = 1; off < 16; off <<= 1) mx = fmaxf(mx, __shfl_xor(mx, off, 64));
      mnew[r] = fmaxf(m_run[r], mx);
      alpha[r] = __expf(m_run[r] - mnew[r]);  // first tile: exp(-huge) = 0
      m_run[r] = mnew[r];
      psum[r] = 0.f;
    }
#pragma unroll
    for (int ct2 = 0; ct2 < 4; ct2++)
#pragma unroll
      for (int r = 0; r < 4; r++) {
        float p = __expf(sv[ct2][r] - mnew[r]);  // masked -> 0
        psum[r] += p;
        Pb[(qd * 4 + r) * 72 + ct2 * 16 + lr] = (__bf16)p;
      }
#pragma unroll
    for (int r = 0; r < 4; r++) {
      float ps = psum[r];
#pragma unroll
      for (int off = 1; off < 16; off <<= 1) ps += __shfl_xor(ps, off, 64);
      l_run[r] = l_run[r] * alpha[r] + ps;
    }
#pragma unroll
    for (int dt = 0; dt < 4; dt++)
#pragma unroll
      for (int r = 0; r < 4; r++) oacc[dt][r] *= alpha[r];

    // O += P V : A-frag from Pb (same wave, same type, in-order LDS),
    // B-frag from Vld[n=d][k=j]
    bf16x8 ap0 = *(const bf16x8*)&Pb[lr * 72 + qd * 8];
    bf16x8 ap1 = *(const bf16x8*)&Pb[lr * 72 + 32 + qd * 8];
#pragma unroll
    for (int dt = 0; dt < 4; dt++) {
      bf16x8 bv0 = *(const bf16x8*)&Vld[(dt * 16 + lr) * 72 + qd * 8];
      bf16x8 bv1 = *(const bf16x8*)&Vld[(dt * 16 + lr) * 72 + 32 + qd * 8];
      oacc[dt] = __builtin_amdgcn_mfma_f32_16x16x32_bf16(ap0, bv0, oacc[dt], 0, 0, 0);
      oacc[dt] = __builtin_amdgcn_mfma_f32_16x16x32_bf16(ap1, bv1, oacc[dt], 0, 0, 0);
    }
  }

  // epilogue: O / l, write Y[b, l, h*64+d] (bf16 workspace)
#pragma unroll
  for (int dt = 0; dt < 4; dt++)
#pragma unroll
    for (int r = 0; r < 4; r++) {
      int tr = qd * 4 + r;
      int l = i0 + wave * 16 + tr;
      int d = dt * 16 + lr;
      float v = oacc[dt][r] / (l_run[r] + 1e-30f);
      Yg[((size_t)(b * LL) + l) * DD + h * HSS + d] = (__bf16)v;
    }
}

// ---------------------------------------------------------------- launch
extern "C" void kernel_launch(void* const* d_in, const int* in_sizes, int n_in,
                              void* d_out, int out_size, void* d_ws, size_t ws_size,
                              hipStream_t stream) {
  // Reference dtypes: ALL inputs fp32, output fp32.
  const float* x = (const float*)d_in[0];
  const float* Wqkv = (const float*)d_in[1];
  const float* bqkv = (const float*)d_in[2];
  const float* Wproj = (const float*)d_in[3];
  const float* bproj = (const float*)d_in[4];
  const float* Er = (const float*)d_in[5];
  float* out = (float*)d_out;

  // ws: Q,Kt,Vt,Y bf16, 8 MB each = 32 MB exactly (known >= from round-3 probe).
  if (ws_size < 4u * 8388608u) return;

  uint8_t* w = (uint8_t*)d_ws;
  __bf16* Q = (__bf16*)w;  w += (size_t)BB * NHH * LL * HSS * 2;
  __bf16* Kt = (__bf16*)w; w += (size_t)BB * NHH * LL * HSS * 2;
  __bf16* Vt = (__bf16*)w; w += (size_t)BB * NHH * LL * HSS * 2;
  __bf16* Y = (__bf16*)w;  w += (size_t)BB * LL * DD * 2;

  gemm_k<float><<<dim3(3072 / 64, 4096 / 64), 256, 0, stream>>>(
      x, Wqkv, bqkv, 4096, 3072, 1024, 0, nullptr, Q, Kt, Vt);
  flash_k<<<dim3(LL / 64, BB * NHH), 256, 0, stream>>>(Q, Kt, Vt, Er, Y);
  gemm_k<__bf16><<<dim3(1024 / 64, 4096 / 64), 256, 0, stream>>>(
      Y, Wproj, bproj, 4096, 1024, 1024, 1, out, nullptr, nullptr, nullptr);
}